// Round 7
// baseline (453.820 us; speedup 1.0000x reference)
//
#include <hip/hip_runtime.h>
#include <math.h>

typedef unsigned short u16;
typedef unsigned int u32;
typedef __bf16 bf16x8 __attribute__((ext_vector_type(8)));
typedef float f32x4 __attribute__((ext_vector_type(4)));

#define NB 1024   // batch
#define HID 1024

__device__ __forceinline__ float bfu(u16 u) { return __uint_as_float(((u32)u) << 16); }
__device__ __forceinline__ u16 f2bf(float f) {
    u32 u = __float_as_uint(f);
    return (u16)((u + 0x7fffu + ((u >> 16) & 1u)) >> 16);
}
// packed bf16-pair multiply: (a0*b0, a1*b1), round-half-up (cheap, ~0.5ulp)
__device__ __forceinline__ u32 mulbf2(u32 a, u32 b) {
    float a0 = __uint_as_float(a << 16), a1 = __uint_as_float(a & 0xffff0000u);
    float b0 = __uint_as_float(b << 16), b1 = __uint_as_float(b & 0xffff0000u);
    u32 u0 = __float_as_uint(a0 * b0), u1 = __float_as_uint(a1 * b1);
    return ((u0 + 0x8000u) >> 16) | ((u1 + 0x8000u) & 0xffff0000u);
}

#if __has_builtin(__builtin_amdgcn_global_load_lds)
#define HAVE_GLL 1
#else
#define HAVE_GLL 0
#endif

__device__ __forceinline__ void stage16(const void* g, void* ldsbase, int lane) {
#if HAVE_GLL
    typedef const __attribute__((address_space(1))) unsigned char ga_t;
    typedef __attribute__((address_space(3))) unsigned char la_t;
    __builtin_amdgcn_global_load_lds((ga_t*)(unsigned long long)g,
                                     (la_t*)(u32)(unsigned long long)ldsbase,
                                     16, 0, 0);
#else
    *reinterpret_cast<uint4*>((char*)ldsbase + lane * 16) =
        *reinterpret_cast<const uint4*>(g);
#endif
}

#define SBAR __builtin_amdgcn_sched_barrier(0)
#define WBAR __builtin_amdgcn_s_barrier()
#define LKW0 asm volatile("s_waitcnt lgkmcnt(0)" ::: "memory")
#define VW0  asm volatile("s_waitcnt vmcnt(0)" ::: "memory")

// ---------------- 128x128-tile helpers (4 waves, 2x2) -------------------

__device__ __forceinline__ void stage_tile(const u16* src, int ld, u16* dst, int tid) {
    int w = tid >> 6, lane = tid & 63;
#pragma unroll
    for (int q = 0; q < 4; ++q) {
        int rbase = q * 32 + w * 8;
        int row = rbase + (lane >> 3);
        stage16(src + (size_t)row * ld + (lane & 7) * 8, dst + rbase * 64, lane);
    }
}

__device__ __forceinline__ void mfma_block(const u16* As, const u16* Bs,
                                           f32x4 acc[4][4], int wr, int wc, int lane) {
    int lr = lane >> 4, lc = lane & 15;
#pragma unroll
    for (int kc = 0; kc < 64; kc += 32) {
        bf16x8 av[4], bv[4];
#pragma unroll
        for (int it = 0; it < 4; ++it)
            av[it] = *(const bf16x8*)&As[(wr * 64 + it * 16 + lc) * 64 + kc + lr * 8];
#pragma unroll
        for (int nt = 0; nt < 4; ++nt)
            bv[nt] = *(const bf16x8*)&Bs[(wc * 64 + nt * 16 + lc) * 64 + kc + lr * 8];
#pragma unroll
        for (int it = 0; it < 4; ++it)
#pragma unroll
            for (int nt = 0; nt < 4; ++nt)
                acc[it][nt] = __builtin_amdgcn_mfma_f32_16x16x32_bf16(
                    av[it], bv[nt], acc[it][nt], 0, 0, 0);
    }
}

// ---------------------------- prep kernels ------------------------------

__global__ __launch_bounds__(256) void k_cast(const float* in, u16* out, int n) {
    int i = blockIdx.x * 256 + threadIdx.x;
    if (i < n) out[i] = f2bf(in[i]);
}

__global__ __launch_bounds__(256) void k_transposeB(const float* inA, const float* inB,
                                                    u16* outA, u16* outB, int R, int C) {
    const float* in = blockIdx.z ? inB : inA;
    u16* out = blockIdx.z ? outB : outA;
    __shared__ u16 tile[32][33];
    int c0 = blockIdx.x * 32, r0 = blockIdx.y * 32;
    int tx = threadIdx.x, ty = threadIdx.y;  // (32, 8)
#pragma unroll
    for (int dy = 0; dy < 32; dy += 8)
        tile[ty + dy][tx] = f2bf(in[(size_t)(r0 + ty + dy) * C + c0 + tx]);
    __syncthreads();
#pragma unroll
    for (int dy = 0; dy < 32; dy += 8)
        out[(size_t)(c0 + ty + dy) * R + r0 + tx] = tile[tx][ty + dy];
}

__global__ __launch_bounds__(256) void k_layer1(const float* states, const float* tptr,
                                                const float* dW1, const float* db1,
                                                const float* nW1, const float* nb1,
                                                u16* h1d, u16* h1n, u16* g1d) {
    __shared__ float xt[129][8];
    int blk = blockIdx.x, q = blockIdx.y, net = blockIdx.z, tid = threadIdx.x;
    float t = *tptr;
    for (int idx = tid; idx < 8 * 128; idx += 256) {
        int d = idx >> 3, s = idx & 7;
        xt[d][s] = states[(size_t)(blk * 8 + s) * 256 + d];
    }
    if (tid < 8) xt[128][tid] = t;
    __syncthreads();
    const float* W = net ? nW1 : dW1;
    const float* bi = net ? nb1 : db1;
    u16* H = net ? h1n : h1d;
    int o = q * 256 + tid;
    float acc[8] = {0.f, 0.f, 0.f, 0.f, 0.f, 0.f, 0.f, 0.f};
    for (int d = 0; d < 129; ++d) {
        float w = W[(size_t)d * 1024 + o];
        float4 xa = *(const float4*)&xt[d][0];
        float4 xb = *(const float4*)&xt[d][4];
        acc[0] += xa.x * w; acc[1] += xa.y * w; acc[2] += xa.z * w; acc[3] += xa.w * w;
        acc[4] += xb.x * w; acc[5] += xb.y * w; acc[6] += xb.z * w; acc[7] += xb.w * w;
    }
    float b = bi[o];
#pragma unroll
    for (int s = 0; s < 8; ++s) {
        float h = tanhf(acc[s] + b);
        H[(size_t)(blk * 8 + s) * 1024 + o] = f2bf(h);
        if (!net) g1d[(size_t)(blk * 8 + s) * 1024 + o] = f2bf(1.f - h * h);
    }
}

__global__ __launch_bounds__(256) void k_l2part(const u16* Ad, const u16* An,
                                                const u16* Wd, const u16* Wn,
                                                float* P) {
    int x = blockIdx.x;
    int nt = x & 7, ks = x >> 3;
    int mt = blockIdx.y, net = blockIdx.z;
    const u16* A = net ? An : Ad;
    const u16* W = net ? Wn : Wd;
    int n0 = nt * 128, row0 = mt * 128;
    int kbeg = ks * 512;
    __shared__ __align__(16) u16 As[128 * 64], Bs[128 * 64];
    int tid = threadIdx.x, w = tid >> 6, lane = tid & 63;
    int wr = w >> 1, wc = w & 1, lr = lane >> 4, lc = lane & 15;
    f32x4 acc[4][4];
#pragma unroll
    for (int a = 0; a < 4; ++a)
#pragma unroll
        for (int b2 = 0; b2 < 4; ++b2) { f32x4 zz = {0.f, 0.f, 0.f, 0.f}; acc[a][b2] = zz; }
    for (int k0 = kbeg; k0 < kbeg + 512; k0 += 64) {
        stage_tile(A + (size_t)row0 * 1024 + k0, 1024, As, tid);
        stage_tile(W + (size_t)n0 * 1024 + k0, 1024, Bs, tid);
        __syncthreads();
        mfma_block(As, Bs, acc, wr, wc, lane);
        __syncthreads();
    }
    float* dst = P + (size_t)(net * 2 + ks) * 1024 * 1024;
#pragma unroll
    for (int it = 0; it < 4; ++it)
#pragma unroll
        for (int nt2 = 0; nt2 < 4; ++nt2) {
            int col = n0 + wc * 64 + nt2 * 16 + lc;
#pragma unroll
            for (int r = 0; r < 4; ++r) {
                int row = row0 + wr * 64 + it * 16 + lr * 4 + r;
                dst[(size_t)row * 1024 + col] = acc[it][nt2][r];
            }
        }
}

__global__ __launch_bounds__(256) void k_h2fin(const float* P, const float* db2,
                                               const float* nb2, u16* h2d, u16* h2n) {
    int net = blockIdx.y;
    const float* b = net ? nb2 : db2;
    u16* H = net ? h2n : h2d;
    size_t idx = (size_t)blockIdx.x * 256 + threadIdx.x;  // < 1M
    int col = (int)(idx & 1023);
    const float* P0 = P + (size_t)(net * 2) * 1024 * 1024;
    const float* P1 = P + (size_t)(net * 2 + 1) * 1024 * 1024;
    H[idx] = f2bf(tanhf(P0[idx] + P1[idx] + b[col]));
}

__global__ __launch_bounds__(256) void k_l3part(const u16* Ad, const u16* An,
                                                const u16* Wd, const u16* Wn,
                                                float* P) {
    int ks = blockIdx.x, mt = blockIdx.y, net = blockIdx.z;
    const u16* A = net ? An : Ad;
    const u16* W = net ? Wn : Wd;
    int row0 = mt * 128, kbeg = ks * 256;
    __shared__ __align__(16) u16 As[128 * 64], Bs[128 * 64];
    int tid = threadIdx.x, w = tid >> 6, lane = tid & 63;
    int wr = w >> 1, wc = w & 1, lr = lane >> 4, lc = lane & 15;
    f32x4 acc[4][4];
#pragma unroll
    for (int a = 0; a < 4; ++a)
#pragma unroll
        for (int b2 = 0; b2 < 4; ++b2) { f32x4 zz = {0.f, 0.f, 0.f, 0.f}; acc[a][b2] = zz; }
    for (int k0 = kbeg; k0 < kbeg + 256; k0 += 64) {
        stage_tile(A + (size_t)row0 * 1024 + k0, 1024, As, tid);
        stage_tile(W + (size_t)k0, 1024, Bs, tid);
        __syncthreads();
        mfma_block(As, Bs, acc, wr, wc, lane);
        __syncthreads();
    }
    float* dst = P + (size_t)(net * 4 + ks) * 1024 * 128;
#pragma unroll
    for (int it = 0; it < 4; ++it)
#pragma unroll
        for (int nt2 = 0; nt2 < 4; ++nt2) {
            int col = wc * 64 + nt2 * 16 + lc;
#pragma unroll
            for (int r = 0; r < 4; ++r) {
                int row = row0 + wr * 64 + it * 16 + lr * 4 + r;
                dst[(size_t)row * 128 + col] = acc[it][nt2][r];
            }
        }
}

// ---- 256x256 8-phase jac GEMM with FUSED g1-scale (L2-resident) --------
// 512 thr = 8 waves (2M x 4N), wave tile 128x64 (8x4 frags of 16x16x32).
// LDS: 2 dbuf x {A[256x64], B[256x64]} bf16 = 128 KiB.
// Per K-tile u: 4 phases, each {ds_read subtile || one staging action ->
// barrier -> lgkmcnt(0) -> setprio+16 MFMA -> barrier}. Staging spread:
// B(u+1) gll half0@ph1 half1@ph2 (counted, drained @ph4 = 2-phase cover),
// issueA(u+1) reg loads@ph3, writeA(u+1) scale+swizzled ds_write@ph4
// (lgkm-drained before tile-boundary barrier for cross-wave visibility).
// Swizzle (r3/r6, measured 0 conflicts): source/write chunk c^(row&7),
// read chunk (kh*4+lr)^(row&7).

__device__ __forceinline__ void stage256h(const u16* panel, int k0, int h,
                                          u16* dst, int tid) {
    int lane = tid & 63, w = tid >> 6;
#pragma unroll
    for (int qq = 0; qq < 2; ++qq) {
        int q = h * 2 + qq;
        int Dhalf = q * 4096 + w * 512 + lane * 8;   // dest offset in u16
        int row = Dhalf >> 6;                        // 64 u16 per row
        int chunk = (Dhalf >> 3) & 7;
        int src_chunk = chunk ^ (row & 7);
        stage16(panel + (size_t)row * 1024 + k0 + src_chunk * 8,
                dst + q * 4096 + w * 512, lane);
    }
}

struct ARegs { uint4 wv[4]; uint4 gv[4]; };

__device__ __forceinline__ void issueA(const u16* dW1bf, const u16* g1d, int mt,
                                       int k0, int tid, ARegs& ar) {
#pragma unroll
    for (int q = 0; q < 4; ++q) {
        int cid = q * 512 + tid;       // 16B-chunk id 0..2047
        int r = cid >> 3, c = cid & 7; // tile row, chunk-in-row
        ar.wv[q] = *(const uint4*)&dW1bf[(size_t)(r & 127) * 1024 + k0 + c * 8];
        ar.gv[q] = *(const uint4*)&g1d[(size_t)(2 * mt + (r >> 7)) * 1024 + k0 + c * 8];
    }
}

__device__ __forceinline__ void writeA(u16* As_, int tid, const ARegs& ar) {
#pragma unroll
    for (int q = 0; q < 4; ++q) {
        int cid = q * 512 + tid;
        int r = cid >> 3, c = cid & 7;
        uint4 o;
        o.x = mulbf2(ar.wv[q].x, ar.gv[q].x);
        o.y = mulbf2(ar.wv[q].y, ar.gv[q].y);
        o.z = mulbf2(ar.wv[q].z, ar.gv[q].z);
        o.w = mulbf2(ar.wv[q].w, ar.gv[q].w);
        *(uint4*)&As_[r * 64 + ((c ^ (r & 7)) << 3)] = o;
    }
}

__device__ __forceinline__ bf16x8 rdA(const u16* T, int wr, int m, int lc, int kq) {
    int row = wr * 128 + m * 16 + lc;
    return *(const bf16x8*)&T[row * 64 + ((kq ^ (row & 7)) << 3)];
}
__device__ __forceinline__ bf16x8 rdB(const u16* T, int wc, int n, int lc, int kq) {
    int row = wc * 64 + n * 16 + lc;
    return *(const bf16x8*)&T[row * 64 + ((kq ^ (row & 7)) << 3)];
}

#define MFMA16(AV, B0, B1, N0, N1)                                          \
    __builtin_amdgcn_s_setprio(1);                                          \
    _Pragma("unroll")                                                       \
    for (int m_ = 0; m_ < 8; ++m_) {                                        \
        acc[m_][N0] = __builtin_amdgcn_mfma_f32_16x16x32_bf16(AV[m_], B0,   \
                                                              acc[m_][N0], 0, 0, 0); \
        acc[m_][N1] = __builtin_amdgcn_mfma_f32_16x16x32_bf16(AV[m_], B1,   \
                                                              acc[m_][N1], 0, 0, 0); \
    }                                                                       \
    __builtin_amdgcn_s_setprio(0);

template <bool STG>
__device__ __forceinline__ void jacf_iter(int t, u16 (*smem)[2][16384],
                                          const u16* dW1bf, const u16* g1d,
                                          const u16* Bp, int mt,
                                          f32x4 (&acc)[8][4], ARegs& ar, int tid,
                                          int wr, int wc, int lr, int lc) {
    int p = t & 1, pn = p ^ 1;
    const u16* As_ = &smem[p][0][0];
    const u16* Bs_ = &smem[p][1][0];
    bf16x8 avA[8], avB[8], bv0, bv1;

    // ---- phase 1: rd avA(kh0)+bv01(kh0); stage B(u+1) half0 ----------
#pragma unroll
    for (int m = 0; m < 8; ++m) avA[m] = rdA(As_, wr, m, lc, lr);
    bv0 = rdB(Bs_, wc, 0, lc, lr);
    bv1 = rdB(Bs_, wc, 1, lc, lr);
    if (STG) stage256h(Bp, (t + 1) * 64, 0, &smem[pn][1][0], tid);
    SBAR; WBAR; LKW0; SBAR;
    MFMA16(avA, bv0, bv1, 0, 1);
    SBAR; WBAR; SBAR;

    // ---- phase 2: rd bv23(kh0)+avB(kh1); stage B(u+1) half1 ----------
    bv0 = rdB(Bs_, wc, 2, lc, lr);
    bv1 = rdB(Bs_, wc, 3, lc, lr);
#pragma unroll
    for (int m = 0; m < 8; ++m) avB[m] = rdA(As_, wr, m, lc, 4 + lr);
    if (STG) stage256h(Bp, (t + 1) * 64, 1, &smem[pn][1][0], tid);
    SBAR; WBAR; LKW0; SBAR;
    MFMA16(avA, bv0, bv1, 2, 3);
    SBAR; WBAR; SBAR;

    // ---- phase 3: rd bv01(kh1); issueA(u+1) reg loads ----------------
    bv0 = rdB(Bs_, wc, 0, lc, 4 + lr);
    bv1 = rdB(Bs_, wc, 1, lc, 4 + lr);
    if (STG) issueA(dW1bf, g1d, mt, (t + 1) * 64, tid, ar);
    SBAR; WBAR; LKW0; SBAR;
    MFMA16(avB, bv0, bv1, 0, 1);
    SBAR; WBAR; SBAR;

    // ---- phase 4: rd bv23(kh1); MFMA; writeA(u+1); drain; boundary ---
    bv0 = rdB(Bs_, wc, 2, lc, 4 + lr);
    bv1 = rdB(Bs_, wc, 3, lc, 4 + lr);
    SBAR; WBAR; LKW0; SBAR;
    MFMA16(avB, bv0, bv1, 2, 3);
    SBAR;
    if (STG) writeA(&smem[pn][0][0], tid, ar);
    VW0;     // B(u+1) glls issued >=2 phases ago -> cheap drain
    LKW0;    // flush ds_writes for cross-wave visibility
    SBAR; WBAR; SBAR;
}

__global__ __launch_bounds__(512, 2) void k_jacf(const u16* dW1bf, const u16* g1d,
                                                 const u16* W2T, const u16* W3T,
                                                 const u16* h2d, float* Jpart) {
    __shared__ __align__(16) u16 smem[2][2][16384];  // [dbuf][A,B][256*64]
    int tid = threadIdx.x, lane = tid & 63, w = tid >> 6;
    int wr = w >> 2, wc = w & 3, lr = lane >> 4, lc = lane & 15;
    int hID = blockIdx.x;                            // 0..2047
    int lin = (hID & 7) * 256 + (hID >> 3);          // XCD-contiguous remap
    int mt = lin >> 2, nt = lin & 3;                 // mt 0..511, nt 0..3
    int n0 = nt * 256;
    const u16* Bp = W2T + (size_t)n0 * 1024;

    f32x4 acc[8][4];
#pragma unroll
    for (int m = 0; m < 8; ++m)
#pragma unroll
        for (int n = 0; n < 4; ++n) { f32x4 zz = {0.f, 0.f, 0.f, 0.f}; acc[m][n] = zz; }

    ARegs ar;
    // prologue: tile 0 (A reg-staged+scaled, B gll)
    issueA(dW1bf, g1d, mt, 0, tid, ar);
    stage256h(Bp, 0, 0, &smem[0][1][0], tid);
    stage256h(Bp, 0, 1, &smem[0][1][0], tid);
    writeA(&smem[0][0][0], tid, ar);
    VW0; LKW0; SBAR; WBAR; SBAR;

    for (int t = 0; t < 15; ++t)
        jacf_iter<true>(t, smem, dW1bf, g1d, Bp, mt, acc, ar, tid, wr, wc, lr, lc);
    jacf_iter<false>(15, smem, dW1bf, g1d, Bp, mt, acc, ar, tid, wr, wc, lr, lc);

    // Fused diagonal contraction (r3/r5/r6-verified mapping).
    int b = 2 * mt + wr;
    float g2v[4];
#pragma unroll
    for (int n = 0; n < 4; ++n) {
        int k2 = n0 + wc * 64 + n * 16 + lc;
        float h2 = bfu(h2d[(size_t)b * 1024 + k2]);
        g2v[n] = 1.f - h2 * h2;
    }
    float* jtmp = (float*)&smem[0][0][0];   // [4][256] floats
#pragma unroll
    for (int m = 0; m < 8; ++m) {
#pragma unroll
        for (int r = 0; r < 4; ++r) {
            int i = m * 16 + lr * 4 + r;
            float p = 0.f;
#pragma unroll
            for (int n = 0; n < 4; ++n) {
                int k2 = n0 + wc * 64 + n * 16 + lc;
                float w3 = bfu(W3T[(size_t)i * 1024 + k2]);
                p += acc[m][n][r] * g2v[n] * w3;
            }
#pragma unroll
            for (int msk = 1; msk < 16; msk <<= 1) p += __shfl_xor(p, msk, 64);
            if (lc == 0) jtmp[wc * 256 + wr * 128 + i] = p;
        }
    }
    __syncthreads();
    if (tid < 256) {
        float s = jtmp[tid] + jtmp[256 + tid] + jtmp[512 + tid] + jtmp[768 + tid];
        int bb = 2 * mt + (tid >> 7);
        Jpart[((size_t)bb * 4 + nt) * 128 + (tid & 127)] = s;
    }
}

// ------------------------------ finalize --------------------------------
__global__ __launch_bounds__(128) void k_final(const float* states, const float* Jpart,
                                               const float* L3part, const float* db3,
                                               const float* nb3, float* out) {
    int b = blockIdx.x, i = threadIdx.x;
    float jd = 0.f;
#pragma unroll
    for (int kb = 0; kb < 4; ++kb) jd += Jpart[((size_t)b * 4 + kb) * 128 + i];
    float mu = db3[i], qr = nb3[i];
#pragma unroll
    for (int ks = 0; ks < 4; ++ks) {
        mu += L3part[((size_t)(0 * 4 + ks) * 1024 + b) * 128 + i];
        qr += L3part[((size_t)(1 * 4 + ks) * 1024 + b) * 128 + i];
    }
    out[(size_t)b * 256 + i] = mu;
    float q = (qr > 20.f) ? qr : log1pf(expf(qr));
    float sig = states[(size_t)b * 256 + 128 + i];
    out[(size_t)b * 256 + 128 + i] = 2.f * jd * sig + q;
    float s1 = jd;
    float s2 = q / (sig + 1e-6f);
#pragma unroll
    for (int m = 32; m >= 1; m >>= 1) {
        s1 += __shfl_down(s1, m, 64);
        s2 += __shfl_down(s2, m, 64);
    }
    __shared__ float red[4];
    int wv = i >> 6, ln = i & 63;
    if (ln == 0) { red[wv * 2] = s1; red[wv * 2 + 1] = s2; }
    __syncthreads();
    if (i == 0) out[(size_t)NB * 256 + b] = -(red[0] + red[2]) + 0.5f * (red[1] + red[3]);
}

extern "C" void kernel_launch(void* const* d_in, const int* in_sizes, int n_in,
                              void* d_out, int out_size, void* d_ws, size_t ws_size,
                              hipStream_t stream) {
    (void)in_sizes; (void)n_in; (void)out_size; (void)ws_size;
    const float* states = (const float*)d_in[0];
    const float* tptr   = (const float*)d_in[1];
    const float* dW1 = (const float*)d_in[2];  const float* db1 = (const float*)d_in[3];
    const float* dW2 = (const float*)d_in[4];  const float* db2 = (const float*)d_in[5];
    const float* dW3 = (const float*)d_in[6];  const float* db3 = (const float*)d_in[7];
    const float* nW1 = (const float*)d_in[8];  const float* nb1 = (const float*)d_in[9];
    const float* nW2 = (const float*)d_in[10]; const float* nb2 = (const float*)d_in[11];
    const float* nW3 = (const float*)d_in[12]; const float* nb3 = (const float*)d_in[13];
    float* out = (float*)d_out;
    char* ws = (char*)d_ws;

    // workspace layout (bytes)
    u16* dW1bf = (u16*)(ws + 0);           //  128x1024 bf16     256 KiB
    u16* dW2T  = (u16*)(ws + 262144);      // 1024x1024 bf16 (T)   2 MiB
    u16* nW2T  = (u16*)(ws + 2359296);     //                      2 MiB
    u16* dW3T  = (u16*)(ws + 4456448);     //  128x1024 bf16 (T) 256 KiB
    u16* nW3T  = (u16*)(ws + 4718592);     //                    256 KiB
    u16* h1d   = (u16*)(ws + 4980736);     // 1024x1024 bf16       2 MiB
    u16* h1n   = (u16*)(ws + 7077888);
    u16* h2d   = (u16*)(ws + 9175040);
    u16* h2n   = (u16*)(ws + 11272192);
    u16* g1d   = (u16*)(ws + 13369344);    // 1024x1024 bf16       2 MiB
    float* Jpart  = (float*)(ws + 15466496);  // 1024x4x128 f32    2 MiB
    float* L3part = (float*)(ws + 17563648);  // 2x4x1024x128 f32  4 MiB
    float* H2part = (float*)(ws + 21757952);  // 2x2x1024x1024 f32 16 MiB

    k_cast<<<512, 256, 0, stream>>>(dW1, dW1bf, 128 * 1024);
    dim3 tb(32, 8);
    k_transposeB<<<dim3(32, 32, 2), tb, 0, stream>>>(dW2, nW2, dW2T, nW2T, 1024, 1024);
    k_transposeB<<<dim3(4, 32, 2), tb, 0, stream>>>(dW3, nW3, dW3T, nW3T, 1024, 128);
    k_layer1<<<dim3(128, 4, 2), 256, 0, stream>>>(states, tptr, dW1, db1, nW1, nb1,
                                                  h1d, h1n, g1d);
    k_l2part<<<dim3(16, 8, 2), 256, 0, stream>>>(h1d, h1n, dW2T, nW2T, H2part);
    k_h2fin<<<dim3(4096, 2), 256, 0, stream>>>(H2part, db2, nb2, h2d, h2n);
    k_l3part<<<dim3(4, 8, 2), 256, 0, stream>>>(h2d, h2n, dW3T, nW3T, L3part);
    k_jacf<<<2048, 512, 0, stream>>>(dW1bf, g1d, dW2T, dW3T, h2d, Jpart);
    k_final<<<1024, 128, 0, stream>>>(states, Jpart, L3part, db3, nb3, out);
}

// Round 8
// 381.668 us; speedup vs baseline: 1.1890x; 1.1890x over previous
//
#include <hip/hip_runtime.h>
#include <math.h>

typedef unsigned short u16;
typedef unsigned int u32;
typedef __bf16 bf16x8 __attribute__((ext_vector_type(8)));
typedef float f32x4 __attribute__((ext_vector_type(4)));

#define NB 1024   // batch
#define HID 1024

__device__ __forceinline__ float bfu(u16 u) { return __uint_as_float(((u32)u) << 16); }
__device__ __forceinline__ u16 f2bf(float f) {
    u32 u = __float_as_uint(f);
    return (u16)((u + 0x7fffu + ((u >> 16) & 1u)) >> 16);
}
// packed bf16-pair multiply: (a0*b0, a1*b1), round-half-up (cheap, ~0.5ulp)
__device__ __forceinline__ u32 mulbf2(u32 a, u32 b) {
    float a0 = __uint_as_float(a << 16), a1 = __uint_as_float(a & 0xffff0000u);
    float b0 = __uint_as_float(b << 16), b1 = __uint_as_float(b & 0xffff0000u);
    u32 u0 = __float_as_uint(a0 * b0), u1 = __float_as_uint(a1 * b1);
    return ((u0 + 0x8000u) >> 16) | ((u1 + 0x8000u) & 0xffff0000u);
}

#if __has_builtin(__builtin_amdgcn_global_load_lds)
#define HAVE_GLL 1
#else
#define HAVE_GLL 0
#endif

__device__ __forceinline__ void stage16(const void* g, void* ldsbase, int lane) {
#if HAVE_GLL
    typedef const __attribute__((address_space(1))) unsigned char ga_t;
    typedef __attribute__((address_space(3))) unsigned char la_t;
    __builtin_amdgcn_global_load_lds((ga_t*)(unsigned long long)g,
                                     (la_t*)(u32)(unsigned long long)ldsbase,
                                     16, 0, 0);
#else
    *reinterpret_cast<uint4*>((char*)ldsbase + lane * 16) =
        *reinterpret_cast<const uint4*>(g);
#endif
}

#define SBAR __builtin_amdgcn_sched_barrier(0)

// ---------------- 128x128-tile helpers (4 waves, 2x2) -------------------

__device__ __forceinline__ void stage_tile(const u16* src, int ld, u16* dst, int tid) {
    int w = tid >> 6, lane = tid & 63;
#pragma unroll
    for (int q = 0; q < 4; ++q) {
        int rbase = q * 32 + w * 8;
        int row = rbase + (lane >> 3);
        stage16(src + (size_t)row * ld + (lane & 7) * 8, dst + rbase * 64, lane);
    }
}

__device__ __forceinline__ void mfma_block(const u16* As, const u16* Bs,
                                           f32x4 acc[4][4], int wr, int wc, int lane) {
    int lr = lane >> 4, lc = lane & 15;
#pragma unroll
    for (int kc = 0; kc < 64; kc += 32) {
        bf16x8 av[4], bv[4];
#pragma unroll
        for (int it = 0; it < 4; ++it)
            av[it] = *(const bf16x8*)&As[(wr * 64 + it * 16 + lc) * 64 + kc + lr * 8];
#pragma unroll
        for (int nt = 0; nt < 4; ++nt)
            bv[nt] = *(const bf16x8*)&Bs[(wc * 64 + nt * 16 + lc) * 64 + kc + lr * 8];
#pragma unroll
        for (int it = 0; it < 4; ++it)
#pragma unroll
            for (int nt = 0; nt < 4; ++nt)
                acc[it][nt] = __builtin_amdgcn_mfma_f32_16x16x32_bf16(
                    av[it], bv[nt], acc[it][nt], 0, 0, 0);
    }
}

// ---------------------------- prep kernels ------------------------------

__global__ __launch_bounds__(256) void k_cast(const float* in, u16* out, int n) {
    int i = blockIdx.x * 256 + threadIdx.x;
    if (i < n) out[i] = f2bf(in[i]);
}

__global__ __launch_bounds__(256) void k_transposeB(const float* inA, const float* inB,
                                                    u16* outA, u16* outB, int R, int C) {
    const float* in = blockIdx.z ? inB : inA;
    u16* out = blockIdx.z ? outB : outA;
    __shared__ u16 tile[32][33];
    int c0 = blockIdx.x * 32, r0 = blockIdx.y * 32;
    int tx = threadIdx.x, ty = threadIdx.y;  // (32, 8)
#pragma unroll
    for (int dy = 0; dy < 32; dy += 8)
        tile[ty + dy][tx] = f2bf(in[(size_t)(r0 + ty + dy) * C + c0 + tx]);
    __syncthreads();
#pragma unroll
    for (int dy = 0; dy < 32; dy += 8)
        out[(size_t)(c0 + ty + dy) * R + r0 + tx] = tile[tx][ty + dy];
}

__global__ __launch_bounds__(256) void k_layer1(const float* states, const float* tptr,
                                                const float* dW1, const float* db1,
                                                const float* nW1, const float* nb1,
                                                u16* h1d, u16* h1n, u16* g1d) {
    __shared__ float xt[129][8];
    int blk = blockIdx.x, q = blockIdx.y, net = blockIdx.z, tid = threadIdx.x;
    float t = *tptr;
    for (int idx = tid; idx < 8 * 128; idx += 256) {
        int d = idx >> 3, s = idx & 7;
        xt[d][s] = states[(size_t)(blk * 8 + s) * 256 + d];
    }
    if (tid < 8) xt[128][tid] = t;
    __syncthreads();
    const float* W = net ? nW1 : dW1;
    const float* bi = net ? nb1 : db1;
    u16* H = net ? h1n : h1d;
    int o = q * 256 + tid;
    float acc[8] = {0.f, 0.f, 0.f, 0.f, 0.f, 0.f, 0.f, 0.f};
    for (int d = 0; d < 129; ++d) {
        float w = W[(size_t)d * 1024 + o];
        float4 xa = *(const float4*)&xt[d][0];
        float4 xb = *(const float4*)&xt[d][4];
        acc[0] += xa.x * w; acc[1] += xa.y * w; acc[2] += xa.z * w; acc[3] += xa.w * w;
        acc[4] += xb.x * w; acc[5] += xb.y * w; acc[6] += xb.z * w; acc[7] += xb.w * w;
    }
    float b = bi[o];
#pragma unroll
    for (int s = 0; s < 8; ++s) {
        float h = tanhf(acc[s] + b);
        H[(size_t)(blk * 8 + s) * 1024 + o] = f2bf(h);
        if (!net) g1d[(size_t)(blk * 8 + s) * 1024 + o] = f2bf(1.f - h * h);
    }
}

__global__ __launch_bounds__(256) void k_l2part(const u16* Ad, const u16* An,
                                                const u16* Wd, const u16* Wn,
                                                float* P) {
    int x = blockIdx.x;
    int nt = x & 7, ks = x >> 3;
    int mt = blockIdx.y, net = blockIdx.z;
    const u16* A = net ? An : Ad;
    const u16* W = net ? Wn : Wd;
    int n0 = nt * 128, row0 = mt * 128;
    int kbeg = ks * 512;
    __shared__ __align__(16) u16 As[128 * 64], Bs[128 * 64];
    int tid = threadIdx.x, w = tid >> 6, lane = tid & 63;
    int wr = w >> 1, wc = w & 1, lr = lane >> 4, lc = lane & 15;
    f32x4 acc[4][4];
#pragma unroll
    for (int a = 0; a < 4; ++a)
#pragma unroll
        for (int b2 = 0; b2 < 4; ++b2) { f32x4 zz = {0.f, 0.f, 0.f, 0.f}; acc[a][b2] = zz; }
    for (int k0 = kbeg; k0 < kbeg + 512; k0 += 64) {
        stage_tile(A + (size_t)row0 * 1024 + k0, 1024, As, tid);
        stage_tile(W + (size_t)n0 * 1024 + k0, 1024, Bs, tid);
        __syncthreads();
        mfma_block(As, Bs, acc, wr, wc, lane);
        __syncthreads();
    }
    float* dst = P + (size_t)(net * 2 + ks) * 1024 * 1024;
#pragma unroll
    for (int it = 0; it < 4; ++it)
#pragma unroll
        for (int nt2 = 0; nt2 < 4; ++nt2) {
            int col = n0 + wc * 64 + nt2 * 16 + lc;
#pragma unroll
            for (int r = 0; r < 4; ++r) {
                int row = row0 + wr * 64 + it * 16 + lr * 4 + r;
                dst[(size_t)row * 1024 + col] = acc[it][nt2][r];
            }
        }
}

__global__ __launch_bounds__(256) void k_h2fin(const float* P, const float* db2,
                                               const float* nb2, u16* h2d, u16* h2n) {
    int net = blockIdx.y;
    const float* b = net ? nb2 : db2;
    u16* H = net ? h2n : h2d;
    size_t idx = (size_t)blockIdx.x * 256 + threadIdx.x;  // < 1M
    int col = (int)(idx & 1023);
    const float* P0 = P + (size_t)(net * 2) * 1024 * 1024;
    const float* P1 = P + (size_t)(net * 2 + 1) * 1024 * 1024;
    H[idx] = f2bf(tanhf(P0[idx] + P1[idx] + b[col]));
}

__global__ __launch_bounds__(256) void k_l3part(const u16* Ad, const u16* An,
                                                const u16* Wd, const u16* Wn,
                                                float* P) {
    int ks = blockIdx.x, mt = blockIdx.y, net = blockIdx.z;
    const u16* A = net ? An : Ad;
    const u16* W = net ? Wn : Wd;
    int row0 = mt * 128, kbeg = ks * 256;
    __shared__ __align__(16) u16 As[128 * 64], Bs[128 * 64];
    int tid = threadIdx.x, w = tid >> 6, lane = tid & 63;
    int wr = w >> 1, wc = w & 1, lr = lane >> 4, lc = lane & 15;
    f32x4 acc[4][4];
#pragma unroll
    for (int a = 0; a < 4; ++a)
#pragma unroll
        for (int b2 = 0; b2 < 4; ++b2) { f32x4 zz = {0.f, 0.f, 0.f, 0.f}; acc[a][b2] = zz; }
    for (int k0 = kbeg; k0 < kbeg + 256; k0 += 64) {
        stage_tile(A + (size_t)row0 * 1024 + k0, 1024, As, tid);
        stage_tile(W + (size_t)k0, 1024, Bs, tid);
        __syncthreads();
        mfma_block(As, Bs, acc, wr, wc, lane);
        __syncthreads();
    }
    float* dst = P + (size_t)(net * 4 + ks) * 1024 * 128;
#pragma unroll
    for (int it = 0; it < 4; ++it)
#pragma unroll
        for (int nt2 = 0; nt2 < 4; ++nt2) {
            int col = wc * 64 + nt2 * 16 + lc;
#pragma unroll
            for (int r = 0; r < 4; ++r) {
                int row = row0 + wr * 64 + it * 16 + lr * 4 + r;
                dst[(size_t)row * 128 + col] = acc[it][nt2][r];
            }
        }
}

// ---- 128x256 jac GEMM, fused g1-scale, 2 blocks/CU (TLP overlap) -------
// 512 thr = 8 waves (2M x 4N), wave tile 64x64 (4x4 frags of 16x16x32).
// BK=32, LDS: 2 dbuf x {A[128x32], B[256x32]} bf16 = 48 KiB -> 2 blocks/CU
// (reg-capped: __launch_bounds__(512,4) => <=128 VGPR+AGPR per thread).
// One block per sample (mt); schedule = r6's proven 2-phase dbuf.
// Swizzle for 64B rows (4 chunks): XOR (row>>1)&3 -> 2-way (free) on both
// ds_write/gll-source and ds_read; analysis: 16-row groups span all 32
// banks with exactly 2 lanes per 16B slot.

__global__ __launch_bounds__(512, 4) void k_jacf(const u16* dW1bf, const u16* g1d,
                                                 const u16* W2T, const u16* W3T,
                                                 const u16* h2d, float* Jpart) {
    __shared__ __align__(16) u16 smA[2][128 * 32];   // 8 KiB each
    __shared__ __align__(16) u16 smB[2][256 * 32];   // 16 KiB each
    int tid = threadIdx.x, lane = tid & 63, w = tid >> 6;
    int wr = w >> 2, wc = w & 3, lr = lane >> 4, lc = lane & 15;
    int hID = blockIdx.x;                            // 0..4095
    int lin = (hID & 7) * 512 + (hID >> 3);          // XCD-contiguous remap
    int mt = lin >> 2, nt = lin & 3;                 // mt = sample 0..1023
    int n0 = nt * 256;
    const u16* Bp = W2T + (size_t)n0 * 1024;
    const u16* grow = g1d + (size_t)mt * 1024;

    f32x4 acc[4][4];
#pragma unroll
    for (int m = 0; m < 4; ++m)
#pragma unroll
        for (int n = 0; n < 4; ++n) { f32x4 zz = {0.f, 0.f, 0.f, 0.f}; acc[m][n] = zz; }

    // A staging: 512 chunks (128 rows x 4), 1 chunk/thread.
    int ar_ = tid >> 2, ac_ = tid & 3;
    int asw = ac_ ^ ((ar_ >> 1) & 3);        // permuted source chunk
    uint4 wv, gv;

    auto issueA = [&](int k0) {
        wv = *(const uint4*)&dW1bf[(size_t)ar_ * 1024 + k0 + asw * 8];
        gv = *(const uint4*)&grow[k0 + asw * 8];
    };
    auto writeA = [&](u16* dst) {
        uint4 o;
        o.x = mulbf2(wv.x, gv.x);
        o.y = mulbf2(wv.y, gv.y);
        o.z = mulbf2(wv.z, gv.z);
        o.w = mulbf2(wv.w, gv.w);
        *(uint4*)&dst[ar_ * 32 + ac_ * 8] = o;
    };
    auto stageB = [&](int k0, u16* dst) {
#pragma unroll
        for (int q = 0; q < 2; ++q) {
            int cid = q * 512 + tid;         // 1024 chunks (256 rows x 4)
            int r = cid >> 2, c = cid & 3;
            stage16(Bp + (size_t)r * 1024 + k0 + ((c ^ ((r >> 1) & 3)) << 3),
                    dst + (q * 512 + w * 64) * 8, lane);
        }
    };
    auto compute = [&](const u16* As_, const u16* Bs_) {
        bf16x8 av[4], bv[4];
#pragma unroll
        for (int m = 0; m < 4; ++m) {
            int row = wr * 64 + m * 16 + lc;
            av[m] = *(const bf16x8*)&As_[row * 32 + ((lr ^ ((row >> 1) & 3)) << 3)];
        }
#pragma unroll
        for (int n = 0; n < 4; ++n) {
            int row = wc * 64 + n * 16 + lc;
            bv[n] = *(const bf16x8*)&Bs_[row * 32 + ((lr ^ ((row >> 1) & 3)) << 3)];
        }
        __builtin_amdgcn_s_setprio(1);
#pragma unroll
        for (int m = 0; m < 4; ++m)
#pragma unroll
            for (int n = 0; n < 4; ++n)
                acc[m][n] = __builtin_amdgcn_mfma_f32_16x16x32_bf16(
                    av[m], bv[n], acc[m][n], 0, 0, 0);
        __builtin_amdgcn_s_setprio(0);
    };

    // prologue: tile 0
    issueA(0);
    stageB(0, smB[0]);
    writeA(smA[0]);
    __syncthreads();

    for (int t = 0; t < 32; ++t) {
        int p = t & 1;
        if (t < 31) {
            issueA((t + 1) * 32);
            stageB((t + 1) * 32, smB[p ^ 1]);
        }
        SBAR;   // pin staging issue before compute
        compute(smA[p], smB[p]);
        if (t < 31) writeA(smA[p ^ 1]);      // write-late (loads have arrived)
        __syncthreads();
    }

    // Fused diagonal contraction (verified C-mapping; 1 sample/block).
    float g2v[4];
#pragma unroll
    for (int n = 0; n < 4; ++n) {
        int k2 = n0 + wc * 64 + n * 16 + lc;
        float h2 = bfu(h2d[(size_t)mt * 1024 + k2]);
        g2v[n] = 1.f - h2 * h2;
    }
    float* jtmp = (float*)&smA[0][0];   // [4][128] floats = 2 KiB
#pragma unroll
    for (int m = 0; m < 4; ++m) {
#pragma unroll
        for (int r = 0; r < 4; ++r) {
            int i = wr * 64 + m * 16 + lr * 4 + r;
            float p = 0.f;
#pragma unroll
            for (int n = 0; n < 4; ++n) {
                int k2 = n0 + wc * 64 + n * 16 + lc;
                float w3 = bfu(W3T[(size_t)i * 1024 + k2]);
                p += acc[m][n][r] * g2v[n] * w3;
            }
#pragma unroll
            for (int msk = 1; msk < 16; msk <<= 1) p += __shfl_xor(p, msk, 64);
            if (lc == 0) jtmp[wc * 128 + i] = p;
        }
    }
    __syncthreads();
    if (tid < 128) {
        float s = jtmp[tid] + jtmp[128 + tid] + jtmp[256 + tid] + jtmp[384 + tid];
        Jpart[((size_t)mt * 4 + nt) * 128 + tid] = s;
    }
}

// ------------------------------ finalize --------------------------------
__global__ __launch_bounds__(128) void k_final(const float* states, const float* Jpart,
                                               const float* L3part, const float* db3,
                                               const float* nb3, float* out) {
    int b = blockIdx.x, i = threadIdx.x;
    float jd = 0.f;
#pragma unroll
    for (int kb = 0; kb < 4; ++kb) jd += Jpart[((size_t)b * 4 + kb) * 128 + i];
    float mu = db3[i], qr = nb3[i];
#pragma unroll
    for (int ks = 0; ks < 4; ++ks) {
        mu += L3part[((size_t)(0 * 4 + ks) * 1024 + b) * 128 + i];
        qr += L3part[((size_t)(1 * 4 + ks) * 1024 + b) * 128 + i];
    }
    out[(size_t)b * 256 + i] = mu;
    float q = (qr > 20.f) ? qr : log1pf(expf(qr));
    float sig = states[(size_t)b * 256 + 128 + i];
    out[(size_t)b * 256 + 128 + i] = 2.f * jd * sig + q;
    float s1 = jd;
    float s2 = q / (sig + 1e-6f);
#pragma unroll
    for (int m = 32; m >= 1; m >>= 1) {
        s1 += __shfl_down(s1, m, 64);
        s2 += __shfl_down(s2, m, 64);
    }
    __shared__ float red[4];
    int wv = i >> 6, ln = i & 63;
    if (ln == 0) { red[wv * 2] = s1; red[wv * 2 + 1] = s2; }
    __syncthreads();
    if (i == 0) out[(size_t)NB * 256 + b] = -(red[0] + red[2]) + 0.5f * (red[1] + red[3]);
}

extern "C" void kernel_launch(void* const* d_in, const int* in_sizes, int n_in,
                              void* d_out, int out_size, void* d_ws, size_t ws_size,
                              hipStream_t stream) {
    (void)in_sizes; (void)n_in; (void)out_size; (void)ws_size;
    const float* states = (const float*)d_in[0];
    const float* tptr   = (const float*)d_in[1];
    const float* dW1 = (const float*)d_in[2];  const float* db1 = (const float*)d_in[3];
    const float* dW2 = (const float*)d_in[4];  const float* db2 = (const float*)d_in[5];
    const float* dW3 = (const float*)d_in[6];  const float* db3 = (const float*)d_in[7];
    const float* nW1 = (const float*)d_in[8];  const float* nb1 = (const float*)d_in[9];
    const float* nW2 = (const float*)d_in[10]; const float* nb2 = (const float*)d_in[11];
    const float* nW3 = (const float*)d_in[12]; const float* nb3 = (const float*)d_in[13];
    float* out = (float*)d_out;
    char* ws = (char*)d_ws;

    // workspace layout (bytes)
    u16* dW1bf = (u16*)(ws + 0);           //  128x1024 bf16     256 KiB
    u16* dW2T  = (u16*)(ws + 262144);      // 1024x1024 bf16 (T)   2 MiB
    u16* nW2T  = (u16*)(ws + 2359296);     //                      2 MiB
    u16* dW3T  = (u16*)(ws + 4456448);     //  128x1024 bf16 (T) 256 KiB
    u16* nW3T  = (u16*)(ws + 4718592);     //                    256 KiB
    u16* h1d   = (u16*)(ws + 4980736);     // 1024x1024 bf16       2 MiB
    u16* h1n   = (u16*)(ws + 7077888);
    u16* h2d   = (u16*)(ws + 9175040);
    u16* h2n   = (u16*)(ws + 11272192);
    u16* g1d   = (u16*)(ws + 13369344);    // 1024x1024 bf16       2 MiB
    float* Jpart  = (float*)(ws + 15466496);  // 1024x4x128 f32    2 MiB
    float* L3part = (float*)(ws + 17563648);  // 2x4x1024x128 f32  4 MiB
    float* H2part = (float*)(ws + 21757952);  // 2x2x1024x1024 f32 16 MiB

    k_cast<<<512, 256, 0, stream>>>(dW1, dW1bf, 128 * 1024);
    dim3 tb(32, 8);
    k_transposeB<<<dim3(32, 32, 2), tb, 0, stream>>>(dW2, nW2, dW2T, nW2T, 1024, 1024);
    k_transposeB<<<dim3(4, 32, 2), tb, 0, stream>>>(dW3, nW3, dW3T, nW3T, 1024, 128);
    k_layer1<<<dim3(128, 4, 2), 256, 0, stream>>>(states, tptr, dW1, db1, nW1, nb1,
                                                  h1d, h1n, g1d);
    k_l2part<<<dim3(16, 8, 2), 256, 0, stream>>>(h1d, h1n, dW2T, nW2T, H2part);
    k_h2fin<<<dim3(4096, 2), 256, 0, stream>>>(H2part, db2, nb2, h2d, h2n);
    k_l3part<<<dim3(4, 8, 2), 256, 0, stream>>>(h2d, h2n, dW3T, nW3T, L3part);
    k_jacf<<<4096, 512, 0, stream>>>(dW1bf, g1d, dW2T, dW3T, h2d, Jpart);
    k_final<<<1024, 128, 0, stream>>>(states, Jpart, L3part, db3, nb3, out);
}

// Round 9
// 347.585 us; speedup vs baseline: 1.3056x; 1.0981x over previous
//
#include <hip/hip_runtime.h>
#include <math.h>

typedef unsigned short u16;
typedef unsigned int u32;
typedef __bf16 bf16x8 __attribute__((ext_vector_type(8)));
typedef float f32x4 __attribute__((ext_vector_type(4)));

#define NB 1024   // batch
#define HID 1024

__device__ __forceinline__ float bfu(u16 u) { return __uint_as_float(((u32)u) << 16); }
__device__ __forceinline__ u16 f2bf(float f) {
    u32 u = __float_as_uint(f);
    return (u16)((u + 0x7fffu + ((u >> 16) & 1u)) >> 16);
}

// scale 8 packed bf16 by 8 packed bf16 via scalar casts (compiler emits
// v_cvt_pk_bf16_f32 pairs -- m240: do NOT hand-write cvt_pk)
__device__ __forceinline__ uint4 scale8(uint4 wv, uint4 gv) {
    union U { uint4 u; __bf16 h[8]; } a, g, r;
    a.u = wv; g.u = gv;
#pragma unroll
    for (int e = 0; e < 8; ++e) r.h[e] = (__bf16)((float)a.h[e] * (float)g.h[e]);
    return r.u;
}

#if __has_builtin(__builtin_amdgcn_global_load_lds)
#define HAVE_GLL 1
#else
#define HAVE_GLL 0
#endif

__device__ __forceinline__ void stage16(const void* g, void* ldsbase, int lane) {
#if HAVE_GLL
    typedef const __attribute__((address_space(1))) unsigned char ga_t;
    typedef __attribute__((address_space(3))) unsigned char la_t;
    __builtin_amdgcn_global_load_lds((ga_t*)(unsigned long long)g,
                                     (la_t*)(u32)(unsigned long long)ldsbase,
                                     16, 0, 0);
#else
    *reinterpret_cast<uint4*>((char*)ldsbase + lane * 16) =
        *reinterpret_cast<const uint4*>(g);
#endif
}

#define SBAR __builtin_amdgcn_sched_barrier(0)
#define WBAR __builtin_amdgcn_s_barrier()

// ---------------- 128x128-tile helpers (4 waves, 2x2) -------------------

__device__ __forceinline__ void stage_tile(const u16* src, int ld, u16* dst, int tid) {
    int w = tid >> 6, lane = tid & 63;
#pragma unroll
    for (int q = 0; q < 4; ++q) {
        int rbase = q * 32 + w * 8;
        int row = rbase + (lane >> 3);
        stage16(src + (size_t)row * ld + (lane & 7) * 8, dst + rbase * 64, lane);
    }
}

__device__ __forceinline__ void mfma_block(const u16* As, const u16* Bs,
                                           f32x4 acc[4][4], int wr, int wc, int lane) {
    int lr = lane >> 4, lc = lane & 15;
#pragma unroll
    for (int kc = 0; kc < 64; kc += 32) {
        bf16x8 av[4], bv[4];
#pragma unroll
        for (int it = 0; it < 4; ++it)
            av[it] = *(const bf16x8*)&As[(wr * 64 + it * 16 + lc) * 64 + kc + lr * 8];
#pragma unroll
        for (int nt = 0; nt < 4; ++nt)
            bv[nt] = *(const bf16x8*)&Bs[(wc * 64 + nt * 16 + lc) * 64 + kc + lr * 8];
#pragma unroll
        for (int it = 0; it < 4; ++it)
#pragma unroll
            for (int nt = 0; nt < 4; ++nt)
                acc[it][nt] = __builtin_amdgcn_mfma_f32_16x16x32_bf16(
                    av[it], bv[nt], acc[it][nt], 0, 0, 0);
    }
}

// ---------------------------- prep kernels ------------------------------

__global__ __launch_bounds__(256) void k_cast(const float* in, u16* out, int n) {
    int i = blockIdx.x * 256 + threadIdx.x;
    if (i < n) out[i] = f2bf(in[i]);
}

__global__ __launch_bounds__(256) void k_transposeB(const float* inA, const float* inB,
                                                    u16* outA, u16* outB, int R, int C) {
    const float* in = blockIdx.z ? inB : inA;
    u16* out = blockIdx.z ? outB : outA;
    __shared__ u16 tile[32][33];
    int c0 = blockIdx.x * 32, r0 = blockIdx.y * 32;
    int tx = threadIdx.x, ty = threadIdx.y;  // (32, 8)
#pragma unroll
    for (int dy = 0; dy < 32; dy += 8)
        tile[ty + dy][tx] = f2bf(in[(size_t)(r0 + ty + dy) * C + c0 + tx]);
    __syncthreads();
#pragma unroll
    for (int dy = 0; dy < 32; dy += 8)
        out[(size_t)(c0 + ty + dy) * R + r0 + tx] = tile[tx][ty + dy];
}

__global__ __launch_bounds__(256) void k_layer1(const float* states, const float* tptr,
                                                const float* dW1, const float* db1,
                                                const float* nW1, const float* nb1,
                                                u16* h1d, u16* h1n, u16* g1d) {
    __shared__ float xt[129][8];
    int blk = blockIdx.x, q = blockIdx.y, net = blockIdx.z, tid = threadIdx.x;
    float t = *tptr;
    for (int idx = tid; idx < 8 * 128; idx += 256) {
        int d = idx >> 3, s = idx & 7;
        xt[d][s] = states[(size_t)(blk * 8 + s) * 256 + d];
    }
    if (tid < 8) xt[128][tid] = t;
    __syncthreads();
    const float* W = net ? nW1 : dW1;
    const float* bi = net ? nb1 : db1;
    u16* H = net ? h1n : h1d;
    int o = q * 256 + tid;
    float acc[8] = {0.f, 0.f, 0.f, 0.f, 0.f, 0.f, 0.f, 0.f};
    for (int d = 0; d < 129; ++d) {
        float w = W[(size_t)d * 1024 + o];
        float4 xa = *(const float4*)&xt[d][0];
        float4 xb = *(const float4*)&xt[d][4];
        acc[0] += xa.x * w; acc[1] += xa.y * w; acc[2] += xa.z * w; acc[3] += xa.w * w;
        acc[4] += xb.x * w; acc[5] += xb.y * w; acc[6] += xb.z * w; acc[7] += xb.w * w;
    }
    float b = bi[o];
#pragma unroll
    for (int s = 0; s < 8; ++s) {
        float h = tanhf(acc[s] + b);
        H[(size_t)(blk * 8 + s) * 1024 + o] = f2bf(h);
        if (!net) g1d[(size_t)(blk * 8 + s) * 1024 + o] = f2bf(1.f - h * h);
    }
}

__global__ __launch_bounds__(256) void k_l2part(const u16* Ad, const u16* An,
                                                const u16* Wd, const u16* Wn,
                                                float* P) {
    int x = blockIdx.x;
    int nt = x & 7, ks = x >> 3;
    int mt = blockIdx.y, net = blockIdx.z;
    const u16* A = net ? An : Ad;
    const u16* W = net ? Wn : Wd;
    int n0 = nt * 128, row0 = mt * 128;
    int kbeg = ks * 512;
    __shared__ __align__(16) u16 As[128 * 64], Bs[128 * 64];
    int tid = threadIdx.x, w = tid >> 6, lane = tid & 63;
    int wr = w >> 1, wc = w & 1, lr = lane >> 4, lc = lane & 15;
    f32x4 acc[4][4];
#pragma unroll
    for (int a = 0; a < 4; ++a)
#pragma unroll
        for (int b2 = 0; b2 < 4; ++b2) { f32x4 zz = {0.f, 0.f, 0.f, 0.f}; acc[a][b2] = zz; }
    for (int k0 = kbeg; k0 < kbeg + 512; k0 += 64) {
        stage_tile(A + (size_t)row0 * 1024 + k0, 1024, As, tid);
        stage_tile(W + (size_t)n0 * 1024 + k0, 1024, Bs, tid);
        __syncthreads();
        mfma_block(As, Bs, acc, wr, wc, lane);
        __syncthreads();
    }
    float* dst = P + (size_t)(net * 2 + ks) * 1024 * 1024;
#pragma unroll
    for (int it = 0; it < 4; ++it)
#pragma unroll
        for (int nt2 = 0; nt2 < 4; ++nt2) {
            int col = n0 + wc * 64 + nt2 * 16 + lc;
#pragma unroll
            for (int r = 0; r < 4; ++r) {
                int row = row0 + wr * 64 + it * 16 + lr * 4 + r;
                dst[(size_t)row * 1024 + col] = acc[it][nt2][r];
            }
        }
}

__global__ __launch_bounds__(256) void k_h2fin(const float* P, const float* db2,
                                               const float* nb2, u16* h2d, u16* h2n) {
    int net = blockIdx.y;
    const float* b = net ? nb2 : db2;
    u16* H = net ? h2n : h2d;
    size_t idx = (size_t)blockIdx.x * 256 + threadIdx.x;  // < 1M
    int col = (int)(idx & 1023);
    const float* P0 = P + (size_t)(net * 2) * 1024 * 1024;
    const float* P1 = P + (size_t)(net * 2 + 1) * 1024 * 1024;
    H[idx] = f2bf(tanhf(P0[idx] + P1[idx] + b[col]));
}

__global__ __launch_bounds__(256) void k_l3part(const u16* Ad, const u16* An,
                                                const u16* Wd, const u16* Wn,
                                                float* P) {
    int ks = blockIdx.x, mt = blockIdx.y, net = blockIdx.z;
    const u16* A = net ? An : Ad;
    const u16* W = net ? Wn : Wd;
    int row0 = mt * 128, kbeg = ks * 256;
    __shared__ __align__(16) u16 As[128 * 64], Bs[128 * 64];
    int tid = threadIdx.x, w = tid >> 6, lane = tid & 63;
    int wr = w >> 1, wc = w & 1, lr = lane >> 4, lc = lane & 15;
    f32x4 acc[4][4];
#pragma unroll
    for (int a = 0; a < 4; ++a)
#pragma unroll
        for (int b2 = 0; b2 < 4; ++b2) { f32x4 zz = {0.f, 0.f, 0.f, 0.f}; acc[a][b2] = zz; }
    for (int k0 = kbeg; k0 < kbeg + 256; k0 += 64) {
        stage_tile(A + (size_t)row0 * 1024 + k0, 1024, As, tid);
        stage_tile(W + (size_t)k0, 1024, Bs, tid);
        __syncthreads();
        mfma_block(As, Bs, acc, wr, wc, lane);
        __syncthreads();
    }
    float* dst = P + (size_t)(net * 4 + ks) * 1024 * 128;
#pragma unroll
    for (int it = 0; it < 4; ++it)
#pragma unroll
        for (int nt2 = 0; nt2 < 4; ++nt2) {
            int col = wc * 64 + nt2 * 16 + lc;
#pragma unroll
            for (int r = 0; r < 4; ++r) {
                int row = row0 + wr * 64 + it * 16 + lr * 4 + r;
                dst[(size_t)row * 128 + col] = acc[it][nt2][r];
            }
        }
}

// ---- 128x256 jac GEMM, BK=64, fused g1-scale, 2 blocks/CU --------------
// 512 thr = 8 waves (2M x 4N), wave tile 64x64 (4x4 frags), 16 K-steps.
// LDS: A[128x64] single (16K) + B[2][256x64] dbuf (64K) = 80 KiB
//   -> 2 blocks/CU uses the full 160 KiB pool.
// B prefetched via global_load_lds (latency hidden across a step);
// A reg-staged: loads issued pre-compute, scale8+ds_write between the
// post-compute raw barrier (A reads done) and __syncthreads (drain).
// Swizzle (r3-verified 0-conflict, 8 chunks/row): physical LDS linear,
// source logical chunk = c ^ (row&7); read chunk = kq ^ (row&7). Since
// row&7 == lc&7 for all fragment rows, the read XOR is a per-thread const.

__global__ __launch_bounds__(512, 4) void k_jacf(const u16* dW1bf, const u16* g1d,
                                                 const u16* W2T, const u16* W3T,
                                                 const u16* h2d, float* Jpart) {
    __shared__ __align__(16) u16 smA[128 * 64];       // 16 KiB, single
    __shared__ __align__(16) u16 smB[2][256 * 64];    // 2 x 32 KiB
    int tid = threadIdx.x, lane = tid & 63, w = tid >> 6;
    int wr = w >> 2, wc = w & 3, lr = lane >> 4, lc = lane & 15;
    int hID = blockIdx.x;                             // 0..4095
    int lin = (hID & 7) * 512 + (hID >> 3);           // XCD-contiguous remap
    int mt = lin >> 2, nt = lin & 3;                  // mt = sample 0..1023
    int n0 = nt * 256;

    // staging assignments: thread owns physical chunks (r0,c0) & (r0+64,c0)
    // of A, and (q*64+r0, c0) q=0..3 of B; all share swizzled source col.
    int r0 = tid >> 3, c0 = tid & 7;
    int csw = (c0 ^ (r0 & 7)) * 8;                    // swizzled source col (u16)
    const u16* aptr = dW1bf + (size_t)r0 * 1024 + csw;
    const u16* gptr = g1d + (size_t)mt * 1024 + csw;
    const u16* bptr = W2T + (size_t)(n0 + r0) * 1024 + csw;
    int d0 = r0 * 64 + c0 * 8;                        // A ds_write offsets
    int d1 = d0 + 4096;

    f32x4 acc[4][4];
#pragma unroll
    for (int m = 0; m < 4; ++m)
#pragma unroll
        for (int n = 0; n < 4; ++n) { f32x4 zz = {0.f, 0.f, 0.f, 0.f}; acc[m][n] = zz; }

    int colr = (lr ^ (lc & 7)) * 8;                   // read col, kh=1: ^32

    // prologue: tile 0
    {
        uint4 gv = *(const uint4*)gptr;
        uint4 wv0 = *(const uint4*)aptr;
        uint4 wv1 = *(const uint4*)(aptr + 65536);
#pragma unroll
        for (int q = 0; q < 4; ++q)
            stage16(bptr + q * 65536, smB[0] + (q * 512 + w * 64) * 8, lane);
        aptr += 64; gptr += 64; bptr += 64;
        uint4 s0 = scale8(wv0, gv), s1 = scale8(wv1, gv);
        *(uint4*)&smA[d0] = s0;
        *(uint4*)&smA[d1] = s1;
    }
    __syncthreads();

    for (int t = 0; t < 16; ++t) {
        int p = t & 1;
        uint4 wv0, wv1, gv;
        if (t < 15) {
            gv = *(const uint4*)gptr;
            wv0 = *(const uint4*)aptr;
            wv1 = *(const uint4*)(aptr + 65536);
#pragma unroll
            for (int q = 0; q < 4; ++q)
                stage16(bptr + q * 65536, smB[p ^ 1] + (q * 512 + w * 64) * 8, lane);
            aptr += 64; gptr += 64; bptr += 64;
        }
        SBAR;
        // compute tile t: A from smA, B from smB[p]
        {
            const u16* Bs_ = smB[p];
            __builtin_amdgcn_s_setprio(1);
#pragma unroll
            for (int kh = 0; kh < 2; ++kh) {
                int col = colr ^ (kh * 32);
                bf16x8 av[4], bv[4];
#pragma unroll
                for (int m = 0; m < 4; ++m)
                    av[m] = *(const bf16x8*)&smA[(wr * 64 + m * 16 + lc) * 64 + col];
#pragma unroll
                for (int n = 0; n < 4; ++n)
                    bv[n] = *(const bf16x8*)&Bs_[(wc * 64 + n * 16 + lc) * 64 + col];
#pragma unroll
                for (int m = 0; m < 4; ++m)
#pragma unroll
                    for (int n = 0; n < 4; ++n)
                        acc[m][n] = __builtin_amdgcn_mfma_f32_16x16x32_bf16(
                            av[m], bv[n], acc[m][n], 0, 0, 0);
            }
            __builtin_amdgcn_s_setprio(0);
        }
        SBAR; WBAR; SBAR;              // all waves done reading smA(t)
        if (t < 15) {
            uint4 s0 = scale8(wv0, gv), s1 = scale8(wv1, gv);
            *(uint4*)&smA[d0] = s0;
            *(uint4*)&smA[d1] = s1;
        }
        __syncthreads();               // drain B gll (vmcnt) + A writes (lgkm)
    }

    // Fused diagonal contraction (r8-verified mapping; 1 sample/block).
    float g2v[4];
#pragma unroll
    for (int n = 0; n < 4; ++n) {
        int k2 = n0 + wc * 64 + n * 16 + lc;
        float h2 = bfu(h2d[(size_t)mt * 1024 + k2]);
        g2v[n] = 1.f - h2 * h2;
    }
    float* jtmp = (float*)&smA[0];     // [4][128] floats = 2 KiB
#pragma unroll
    for (int m = 0; m < 4; ++m) {
#pragma unroll
        for (int r = 0; r < 4; ++r) {
            int i = wr * 64 + m * 16 + lr * 4 + r;
            float p = 0.f;
#pragma unroll
            for (int n = 0; n < 4; ++n) {
                int k2 = n0 + wc * 64 + n * 16 + lc;
                float w3 = bfu(W3T[(size_t)i * 1024 + k2]);
                p += acc[m][n][r] * g2v[n] * w3;
            }
#pragma unroll
            for (int msk = 1; msk < 16; msk <<= 1) p += __shfl_xor(p, msk, 64);
            if (lc == 0) jtmp[wc * 128 + i] = p;
        }
    }
    __syncthreads();
    if (tid < 128) {
        float s = jtmp[tid] + jtmp[128 + tid] + jtmp[256 + tid] + jtmp[384 + tid];
        Jpart[((size_t)mt * 4 + nt) * 128 + tid] = s;
    }
}

// ------------------------------ finalize --------------------------------
__global__ __launch_bounds__(128) void k_final(const float* states, const float* Jpart,
                                               const float* L3part, const float* db3,
                                               const float* nb3, float* out) {
    int b = blockIdx.x, i = threadIdx.x;
    float jd = 0.f;
#pragma unroll
    for (int kb = 0; kb < 4; ++kb) jd += Jpart[((size_t)b * 4 + kb) * 128 + i];
    float mu = db3[i], qr = nb3[i];
#pragma unroll
    for (int ks = 0; ks < 4; ++ks) {
        mu += L3part[((size_t)(0 * 4 + ks) * 1024 + b) * 128 + i];
        qr += L3part[((size_t)(1 * 4 + ks) * 1024 + b) * 128 + i];
    }
    out[(size_t)b * 256 + i] = mu;
    float q = (qr > 20.f) ? qr : log1pf(expf(qr));
    float sig = states[(size_t)b * 256 + 128 + i];
    out[(size_t)b * 256 + 128 + i] = 2.f * jd * sig + q;
    float s1 = jd;
    float s2 = q / (sig + 1e-6f);
#pragma unroll
    for (int m = 32; m >= 1; m >>= 1) {
        s1 += __shfl_down(s1, m, 64);
        s2 += __shfl_down(s2, m, 64);
    }
    __shared__ float red[4];
    int wv = i >> 6, ln = i & 63;
    if (ln == 0) { red[wv * 2] = s1; red[wv * 2 + 1] = s2; }
    __syncthreads();
    if (i == 0) out[(size_t)NB * 256 + b] = -(red[0] + red[2]) + 0.5f * (red[1] + red[3]);
}

extern "C" void kernel_launch(void* const* d_in, const int* in_sizes, int n_in,
                              void* d_out, int out_size, void* d_ws, size_t ws_size,
                              hipStream_t stream) {
    (void)in_sizes; (void)n_in; (void)out_size; (void)ws_size;
    const float* states = (const float*)d_in[0];
    const float* tptr   = (const float*)d_in[1];
    const float* dW1 = (const float*)d_in[2];  const float* db1 = (const float*)d_in[3];
    const float* dW2 = (const float*)d_in[4];  const float* db2 = (const float*)d_in[5];
    const float* dW3 = (const float*)d_in[6];  const float* db3 = (const float*)d_in[7];
    const float* nW1 = (const float*)d_in[8];  const float* nb1 = (const float*)d_in[9];
    const float* nW2 = (const float*)d_in[10]; const float* nb2 = (const float*)d_in[11];
    const float* nW3 = (const float*)d_in[12]; const float* nb3 = (const float*)d_in[13];
    float* out = (float*)d_out;
    char* ws = (char*)d_ws;

    // workspace layout (bytes)
    u16* dW1bf = (u16*)(ws + 0);           //  128x1024 bf16     256 KiB
    u16* dW2T  = (u16*)(ws + 262144);      // 1024x1024 bf16 (T)   2 MiB
    u16* nW2T  = (u16*)(ws + 2359296);     //                      2 MiB
    u16* dW3T  = (u16*)(ws + 4456448);     //  128x1024 bf16 (T) 256 KiB
    u16* nW3T  = (u16*)(ws + 4718592);     //                    256 KiB
    u16* h1d   = (u16*)(ws + 4980736);     // 1024x1024 bf16       2 MiB
    u16* h1n   = (u16*)(ws + 7077888);
    u16* h2d   = (u16*)(ws + 9175040);
    u16* h2n   = (u16*)(ws + 11272192);
    u16* g1d   = (u16*)(ws + 13369344);    // 1024x1024 bf16       2 MiB
    float* Jpart  = (float*)(ws + 15466496);  // 1024x4x128 f32    2 MiB
    float* L3part = (float*)(ws + 17563648);  // 2x4x1024x128 f32  4 MiB
    float* H2part = (float*)(ws + 21757952);  // 2x2x1024x1024 f32 16 MiB

    k_cast<<<512, 256, 0, stream>>>(dW1, dW1bf, 128 * 1024);
    dim3 tb(32, 8);
    k_transposeB<<<dim3(32, 32, 2), tb, 0, stream>>>(dW2, nW2, dW2T, nW2T, 1024, 1024);
    k_transposeB<<<dim3(4, 32, 2), tb, 0, stream>>>(dW3, nW3, dW3T, nW3T, 1024, 128);
    k_layer1<<<dim3(128, 4, 2), 256, 0, stream>>>(states, tptr, dW1, db1, nW1, nb1,
                                                  h1d, h1n, g1d);
    k_l2part<<<dim3(16, 8, 2), 256, 0, stream>>>(h1d, h1n, dW2T, nW2T, H2part);
    k_h2fin<<<dim3(4096, 2), 256, 0, stream>>>(H2part, db2, nb2, h2d, h2n);
    k_l3part<<<dim3(4, 8, 2), 256, 0, stream>>>(h2d, h2n, dW3T, nW3T, L3part);
    k_jacf<<<4096, 512, 0, stream>>>(dW1bf, g1d, dW2T, dW3T, h2d, Jpart);
    k_final<<<1024, 128, 0, stream>>>(states, Jpart, L3part, db3, nb3, out);
}